// Round 3
// baseline (341.262 us; speedup 1.0000x reference)
//
#include <hip/hip_runtime.h>
#include <stdint.h>

typedef __bf16 bf16x8 __attribute__((ext_vector_type(8)));
typedef float f32x4 __attribute__((ext_vector_type(4)));
typedef unsigned short u16;

__device__ __forceinline__ u16 f2bf(float f){
  uint32_t u = __float_as_uint(f);
  u = (u + 0x7fffu + ((u >> 16) & 1u)) >> 16;
  return (u16)u;
}

__device__ __forceinline__ void gl_lds16(const void* g, void* l){
  __builtin_amdgcn_global_load_lds((const __attribute__((address_space(1))) void*)g,
                                   (__attribute__((address_space(3))) void*)l, 16, 0, 0);
}

// ---------------------------------------------------------------------------
// Weight prep
// ---------------------------------------------------------------------------
__global__ void cvt_f32_bf16(const float* __restrict__ in, u16* __restrict__ out, int n){
  int i = blockIdx.x*256 + threadIdx.x;
  if (i < n) out[i] = f2bf(in[i]);
}

// w2 [O=256][C=256][3][3] f32 -> wb2 [O][kq=ky*3+kx][C] bf16
__global__ void prep_w2k(const float* __restrict__ in, u16* __restrict__ out){
  int i = blockIdx.x*256 + threadIdx.x;
  if (i < 589824){
    int o = i / 2304, r = i - o*2304, kq = r >> 8, c = r & 255;
    out[i] = f2bf(in[((size_t)o*256 + c)*9 + kq]);
  }
}

// ---------------------------------------------------------------------------
// x [128][1024][196] f32 NCHW -> xp0 [b*196+p][1024] bf16
// ---------------------------------------------------------------------------
__global__ __launch_bounds__(256) void transform_x(const float* __restrict__ x,
                                                   u16* __restrict__ xp0){
  __shared__ float lds[64*201];
  const int b = blockIdx.y, c0 = blockIdx.x*64, t = threadIdx.x;
  const float4* src = (const float4*)x + (size_t)b*50176 + (size_t)c0*49;
  #pragma unroll
  for (int r = 0; r < 13; ++r){
    int q = r*256 + t;
    if (q < 3136){
      unsigned c = (unsigned)q / 49u, f = (unsigned)q - c*49u;
      float4 v = src[q];
      float* d = &lds[c*201 + f*4];
      d[0]=v.x; d[1]=v.y; d[2]=v.z; d[3]=v.w;
    }
  }
  __syncthreads();
  const int c4 = (t & 15)*4, pg = t >> 4;
  #pragma unroll
  for (int r = 0; r < 13; ++r){
    int p = r*16 + pg;
    if (p < 196){
      ushort4 pk;
      ((u16*)&pk)[0] = f2bf(lds[(c4+0)*201 + p]);
      ((u16*)&pk)[1] = f2bf(lds[(c4+1)*201 + p]);
      ((u16*)&pk)[2] = f2bf(lds[(c4+2)*201 + p]);
      ((u16*)&pk)[3] = f2bf(lds[(c4+3)*201 + p]);
      *(ushort4*)&xp0[((size_t)b*196 + p)*1024 + c0 + c4] = pk;
    }
  }
}

// ---------------------------------------------------------------------------
// Zero conv2's SAME-padding border rows of xp1
// ---------------------------------------------------------------------------
__global__ void zfill_borders(u16* __restrict__ xp1){
  int tid = blockIdx.x*256 + threadIdx.x;
  int row_i = tid >> 5, w = tid & 31;
  unsigned b = (unsigned)row_i / 60u, k = (unsigned)row_i - b*60u;
  int y, xx;
  if (k < 32){ y = (k>>4)*15; xx = k & 15; }
  else if (k < 46){ y = k - 31; xx = 0; }
  else { y = k - 45; xx = 15; }
  size_t row = (size_t)b*256 + y*16 + xx;
  ((ulonglong2*)(xp1 + row*256))[w] = (ulonglong2){0,0};
}

// ---------------------------------------------------------------------------
// MFMA GEMM: C[m][n] = sum_k A[m][k]*B[k][n]
// CID 1,2: BM=128 BN=64, double-buffered, 3 blocks/CU
// CID 3:   BM=128 BN=128, single buffer + LDS-transposed f32 epilogue
// ---------------------------------------------------------------------------
template<int CID>
__global__ __launch_bounds__(256, (CID==3) ? 4 : 3) void gemm_k(
    const u16* __restrict__ A, const u16* __restrict__ B,
    u16* __restrict__ Obf, float* __restrict__ Of32, const float* __restrict__ xres,
    const float* __restrict__ s0, const float* __restrict__ s1, const float* __restrict__ s2)
{
  constexpr int KTOT  = (CID==1) ? 1024 : (CID==2) ? 2304 : 256;
  constexpr int NSTEP = KTOT / 64;
  constexpr int BN    = (CID==3) ? 128 : 64;
  constexpr int WN    = (CID==3) ? 64 : 32;
  constexpr int NJ    = WN / 16;
  constexpr int NBG   = BN*8/256;            // B granules per thread (2 or 4)
  constexpr int BUFB  = 16384 + BN*128;      // bytes per LDS buffer
  constexpr size_t LDSZ = (CID==3) ? 33792 : 2*(size_t)BUFB;

  __shared__ char lds[LDSZ];
  const int t    = threadIdx.x;
  const int lane = t & 63;
  const int w    = t >> 6;
  const int wm   = (w >> 1) * 64, wn = (w & 1) * WN;
  const int m0   = blockIdx.y * 128, n0 = blockIdx.x * BN;

  f32x4 acc[4][NJ] = {};

  uint32_t aoff[4], boff[NBG];
  #pragma unroll
  for (int i = 0; i < 4; ++i){
    int gl = i*256 + t, row = gl >> 3, ss = gl & 7;
    int xo = (ss ^ (row & 7)) << 4;
    aoff[i] = (uint32_t)(m0 + row) * (KTOT*2) + xo;
  }
  #pragma unroll
  for (int i = 0; i < NBG; ++i){
    int gl = i*256 + t, row = gl >> 3, ss = gl & 7;
    int xo = (ss ^ (row & 7)) << 4;
    uint32_t n = n0 + row;
    if constexpr (CID==1)      boff[i] = n * 2048u + xo;
    else if constexpr (CID==3) boff[i] = n * 512u + xo;
    else {
      uint32_t b = n / 196u, p = n - b*196u;
      uint32_t py = p / 14u,  px = p - py*14u;
      uint32_t prow = b*256u + (py+1)*16u + (px+1);
      boff[i] = prow * 512u + xo;
    }
  }

  auto stage = [&](int buf, int s){
    char* Ab = lds + buf*BUFB;
    char* Bb = Ab + 16384;
    const int ka = s*128;
    int kb;
    if constexpr (CID==2){
      int kq = s >> 2;
      kb = ((kq/3 - 1)*16 + (kq%3) - 1)*512 + (s & 3)*128;
    } else kb = ka;
    #pragma unroll
    for (int i = 0; i < 4; ++i)
      gl_lds16((const char*)A + aoff[i] + ka, Ab + (i*256 + t)*16);
    #pragma unroll
    for (int i = 0; i < NBG; ++i)
      gl_lds16((const char*)B + (int64_t)boff[i] + kb, Bb + (i*256 + t)*16);
  };

  auto compute = [&](int buf){
    char* Ab = lds + buf*BUFB;
    char* Bb = Ab + 16384;
    #pragma unroll
    for (int h = 0; h < 2; ++h){
      bf16x8 af[4], bfr[NJ];
      #pragma unroll
      for (int i = 0; i < 4; ++i){
        int row = wm + i*16 + (lane & 15);
        af[i] = *(const bf16x8*)(Ab + row*128 + (((h*4 + (lane>>4)) ^ (row & 7)) << 4));
      }
      #pragma unroll
      for (int j = 0; j < NJ; ++j){
        int row = wn + j*16 + (lane & 15);
        bfr[j] = *(const bf16x8*)(Bb + row*128 + (((h*4 + (lane>>4)) ^ (row & 7)) << 4));
      }
      #pragma unroll
      for (int i = 0; i < 4; ++i)
        #pragma unroll
        for (int j = 0; j < NJ; ++j)
          acc[i][j] = __builtin_amdgcn_mfma_f32_16x16x32_bf16(af[i], bfr[j], acc[i][j], 0, 0, 0);
    }
  };

  if constexpr (CID==3){
    #pragma unroll
    for (int s = 0; s < NSTEP; ++s){
      if (s) __syncthreads();          // compute done before overwrite
      stage(0, s);
      __syncthreads();                 // drains vmcnt before barrier
      compute(0);
    }
  } else {
    stage(0, 0);
    __syncthreads();
    for (int s = 0; s < NSTEP; ++s){
      if (s + 1 < NSTEP) stage((s+1) & 1, s+1);
      compute(s & 1);
      __syncthreads();
    }
  }

  // ---- epilogue (C/D: col=lane&15 -> n, row=(lane>>4)*4+q -> m) ----
  if constexpr (CID==1 || CID==2){
    float badd = s0[0] + s1[0];
    #pragma unroll
    for (int i = 0; i < 4; ++i){
      int o = m0 + wm + i*16 + ((lane >> 4) << 2);
      #pragma unroll
      for (int j = 0; j < NJ; ++j){
        uint32_t n = n0 + wn + j*16 + (lane & 15);
        size_t rn;
        if constexpr (CID==1){
          uint32_t b = n / 196u, p = n - b*196u;
          uint32_t py = p / 14u, px = p - py*14u;
          rn = (size_t)b*256 + (py+1)*16 + (px+1);
        } else rn = n;
        ushort4 pk;
        #pragma unroll
        for (int q = 0; q < 4; ++q) ((u16*)&pk)[q] = f2bf(acc[i][j][q] + badd);
        *(ushort4*)(Obf + rn*256 + o) = pk;
      }
    }
  } else {
    float b3 = s0[0], rs = s1[0], rbv = s2[0];
    float* ldsF = (float*)lds;                 // [64][132] padded f32 tile
    #pragma unroll
    for (int pass = 0; pass < 2; ++pass){
      __syncthreads();
      if ((wm >> 6) == pass){
        #pragma unroll
        for (int i = 0; i < 4; ++i){
          int rb = i*16 + ((lane >> 4) << 2);
          #pragma unroll
          for (int j = 0; j < 4; ++j){
            int col = wn + j*16 + (lane & 15);
            #pragma unroll
            for (int q = 0; q < 4; ++q) ldsF[(rb + q)*132 + col] = acc[i][j][q];
          }
        }
      }
      __syncthreads();
      #pragma unroll
      for (int r = 0; r < 8; ++r){
        int row = (w << 4) + ((lane >> 5) << 3) + r;     // 0..63
        int n4  = (lane & 31) << 2;
        float4 v = *(float4*)&ldsF[row*132 + n4];
        uint32_t n = n0 + n4;
        uint32_t b = n / 196u, p = n - b*196u;           // 196 % 4 == 0: no straddle
        int o = m0 + pass*64 + row;
        size_t base = ((size_t)b*1024 + o)*196 + p;
        float4 xr = *(const float4*)&xres[base];
        float4 ov;
        ov.x = fmaxf((v.x + b3)*rs + rbv + xr.x, 0.f);
        ov.y = fmaxf((v.y + b3)*rs + rbv + xr.y, 0.f);
        ov.z = fmaxf((v.z + b3)*rs + rbv + xr.z, 0.f);
        ov.w = fmaxf((v.w + b3)*rs + rbv + xr.w, 0.f);
        *(float4*)&Of32[base] = ov;
      }
    }
  }
}

// ---------------------------------------------------------------------------
extern "C" void kernel_launch(void* const* d_in, const int* in_sizes, int n_in,
                              void* d_out, int out_size, void* d_ws, size_t ws_size,
                              hipStream_t stream){
  (void)in_sizes; (void)n_in; (void)out_size; (void)ws_size;
  const float* x   = (const float*)d_in[0];
  const float* w1  = (const float*)d_in[1];
  const float* w2  = (const float*)d_in[2];
  const float* w3  = (const float*)d_in[3];
  const float* b1b = (const float*)d_in[4];
  const float* b2a = (const float*)d_in[5];
  const float* b2b = (const float*)d_in[6];
  const float* b3a = (const float*)d_in[7];
  const float* b3b = (const float*)d_in[8];
  const float* rsc = (const float*)d_in[9];
  const float* rbi = (const float*)d_in[10];

  char* ws  = (char*)d_ws;
  u16*  xp1 = (u16*)ws;                       // 32768 padded rows x 512B
  u16*  xp2 = (u16*)(ws + 16777216);          // 25088 rows x 512B
  u16*  wb1 = (u16*)(ws + 29622272);
  u16*  wb2 = (u16*)(ws + 30146560);
  u16*  wb3 = (u16*)(ws + 31326208);
  u16*  xp0 = (u16*)d_out;                    // conv1 input staged in d_out

  cvt_f32_bf16<<<dim3(1024), 256, 0, stream>>>(w1, wb1, 262144);
  prep_w2k    <<<dim3(2304), 256, 0, stream>>>(w2, wb2);
  cvt_f32_bf16<<<dim3(1024), 256, 0, stream>>>(w3, wb3, 262144);
  transform_x <<<dim3(16,128), 256, 0, stream>>>(x, xp0);
  zfill_borders<<<dim3(960), 256, 0, stream>>>(xp1);

  gemm_k<1><<<dim3(392, 2), 256, 0, stream>>>(wb1, xp0, xp1, nullptr, nullptr, b1b, b2a, nullptr);
  gemm_k<2><<<dim3(392, 2), 256, 0, stream>>>(wb2, xp1, xp2, nullptr, nullptr, b2b, b3a, nullptr);
  gemm_k<3><<<dim3(196, 8), 256, 0, stream>>>(wb3, xp2, nullptr, (float*)d_out, x, b3b, rsc, rbi);
}

// Round 4
// 331.949 us; speedup vs baseline: 1.0281x; 1.0281x over previous
//
#include <hip/hip_runtime.h>
#include <stdint.h>

typedef __bf16 bf16x8 __attribute__((ext_vector_type(8)));
typedef float f32x4 __attribute__((ext_vector_type(4)));
typedef unsigned short u16;

__device__ __forceinline__ u16 f2bf(float f){
  uint32_t u = __float_as_uint(f);
  u = (u + 0x7fffu + ((u >> 16) & 1u)) >> 16;
  return (u16)u;
}
__device__ __forceinline__ float bf2f(u16 v){
  return __uint_as_float(((uint32_t)v) << 16);
}
__device__ __forceinline__ void gl_lds16(const void* g, void* l){
  __builtin_amdgcn_global_load_lds((const __attribute__((address_space(1))) void*)g,
                                   (__attribute__((address_space(3))) void*)l, 16, 0, 0);
}

// ---------------------------------------------------------------------------
// One mega prep kernel: w1/w3 cvt, w2 repack, xp1 border zero-fill
// blocks: [0,1024) w1 | [1024,3328) w2 | [3328,4352) w3 | [4352,5312) zfill
// ---------------------------------------------------------------------------
__global__ __launch_bounds__(256) void prep_all(
    const float* __restrict__ w1, const float* __restrict__ w2,
    const float* __restrict__ w3, u16* __restrict__ wb1, u16* __restrict__ wb2,
    u16* __restrict__ wb3, u16* __restrict__ xp1){
  int bid = blockIdx.x, t = threadIdx.x;
  if (bid < 1024){
    int i = bid*256 + t; wb1[i] = f2bf(w1[i]);
  } else if (bid < 3328){
    int i = (bid-1024)*256 + t;                  // < 589824
    int o = i / 2304, r = i - o*2304, kq = r >> 8, c = r & 255;
    wb2[i] = f2bf(w2[((size_t)o*256 + c)*9 + kq]);
  } else if (bid < 4352){
    int i = (bid-3328)*256 + t; wb3[i] = f2bf(w3[i]);
  } else {
    int tid = (bid-4352)*256 + t;                // 245760 = 7680 rows * 32
    int row_i = tid >> 5, w = tid & 31;
    unsigned b = (unsigned)row_i / 60u, k = (unsigned)row_i - b*60u;
    int y, xx;
    if (k < 32){ y = (k>>4)*15; xx = k & 15; }
    else if (k < 46){ y = k - 31; xx = 0; }
    else { y = k - 45; xx = 15; }
    size_t row = (size_t)b*256 + y*16 + xx;
    ((ulonglong2*)(xp1 + row*256))[w] = (ulonglong2){0,0};
  }
}

// ---------------------------------------------------------------------------
// x [128][1024][196] f32 NCHW -> xp0 [b*196+p][1024] bf16
// ---------------------------------------------------------------------------
__global__ __launch_bounds__(256) void transform_x(const float* __restrict__ x,
                                                   u16* __restrict__ xp0){
  __shared__ float lds[64*201];
  const int b = blockIdx.y, c0 = blockIdx.x*64, t = threadIdx.x;
  const float4* src = (const float4*)x + (size_t)b*50176 + (size_t)c0*49;
  #pragma unroll
  for (int r = 0; r < 13; ++r){
    int q = r*256 + t;
    if (q < 3136){
      unsigned c = (unsigned)q / 49u, f = (unsigned)q - c*49u;
      float4 v = src[q];
      float* d = &lds[c*201 + f*4];
      d[0]=v.x; d[1]=v.y; d[2]=v.z; d[3]=v.w;
    }
  }
  __syncthreads();
  const int c4 = (t & 15)*4, pg = t >> 4;
  #pragma unroll
  for (int r = 0; r < 13; ++r){
    int p = r*16 + pg;
    if (p < 196){
      ushort4 pk;
      ((u16*)&pk)[0] = f2bf(lds[(c4+0)*201 + p]);
      ((u16*)&pk)[1] = f2bf(lds[(c4+1)*201 + p]);
      ((u16*)&pk)[2] = f2bf(lds[(c4+2)*201 + p]);
      ((u16*)&pk)[3] = f2bf(lds[(c4+3)*201 + p]);
      *(ushort4*)&xp0[((size_t)b*196 + p)*1024 + c0 + c4] = pk;
    }
  }
}

// ---------------------------------------------------------------------------
// MFMA GEMM body. CID 1,2: BM128 BN64 dbuf; CID 3: BM128 BN128 single-buf +
// LDS-transposed f32 epilogue w/ bf16 residual. 1D grid, XCD chunk swizzle,
// m-fastest ordering (blocks sharing a B-panel land on the same XCD's L2).
// ---------------------------------------------------------------------------
template<int CID>
__device__ __forceinline__ void gemm_body(
    const u16* __restrict__ A, const u16* __restrict__ B,
    u16* __restrict__ Obf, float* __restrict__ Of32, const u16* __restrict__ xresb,
    const float* __restrict__ s0, const float* __restrict__ s1, const float* __restrict__ s2)
{
  constexpr int KTOT  = (CID==1) ? 1024 : (CID==2) ? 2304 : 256;
  constexpr int NSTEP = KTOT / 64;
  constexpr int BN    = (CID==3) ? 128 : 64;
  constexpr int WN    = (CID==3) ? 64 : 32;
  constexpr int NJ    = WN / 16;
  constexpr int NBG   = BN*8/256;
  constexpr int BUFB  = 16384 + BN*128;
  constexpr int LDSZ  = (CID==3) ? 33792 : 2*BUFB;

  __shared__ char lds[LDSZ];
  const int t    = threadIdx.x;
  const int lane = t & 63;
  const int w    = t >> 6;
  const int wm   = (w >> 1) * 64, wn = (w & 1) * WN;

  // XCD chunk swizzle (nwg % 8 == 0 for all three launches)
  const int orig = blockIdx.x;
  const int bid  = (orig & 7) * ((int)gridDim.x >> 3) + (orig >> 3);
  int n0, m0;
  if constexpr (CID==3){ n0 = (bid >> 3) * 128; m0 = (bid & 7) * 128; }
  else                 { n0 = (bid >> 1) * 64;  m0 = (bid & 1) * 128; }

  f32x4 acc[4][NJ] = {};

  uint32_t aoff[4], boff[NBG];
  #pragma unroll
  for (int i = 0; i < 4; ++i){
    int gl = i*256 + t, row = gl >> 3, ss = gl & 7;
    int xo = (ss ^ (row & 7)) << 4;
    aoff[i] = (uint32_t)(m0 + row) * (KTOT*2) + xo;
  }
  #pragma unroll
  for (int i = 0; i < NBG; ++i){
    int gl = i*256 + t, row = gl >> 3, ss = gl & 7;
    int xo = (ss ^ (row & 7)) << 4;
    uint32_t n = n0 + row;
    if constexpr (CID==1)      boff[i] = n * 2048u + xo;
    else if constexpr (CID==3) boff[i] = n * 512u + xo;
    else {
      uint32_t b = n / 196u, p = n - b*196u;
      uint32_t py = p / 14u,  px = p - py*14u;
      uint32_t prow = b*256u + (py+1)*16u + (px+1);
      boff[i] = prow * 512u + xo;
    }
  }

  auto stage = [&](int buf, int s){
    char* Ab = lds + buf*BUFB;
    char* Bb = Ab + 16384;
    const int ka = s*128;
    int kb;
    if constexpr (CID==2){
      int kq = s >> 2;
      kb = ((kq/3 - 1)*16 + (kq%3) - 1)*512 + (s & 3)*128;
    } else kb = ka;
    #pragma unroll
    for (int i = 0; i < 4; ++i)
      gl_lds16((const char*)A + aoff[i] + ka, Ab + (i*256 + t)*16);
    #pragma unroll
    for (int i = 0; i < NBG; ++i)
      gl_lds16((const char*)B + (int64_t)boff[i] + kb, Bb + (i*256 + t)*16);
  };

  auto compute = [&](int buf){
    char* Ab = lds + buf*BUFB;
    char* Bb = Ab + 16384;
    #pragma unroll
    for (int h = 0; h < 2; ++h){
      bf16x8 af[4], bfr[NJ];
      #pragma unroll
      for (int i = 0; i < 4; ++i){
        int row = wm + i*16 + (lane & 15);
        af[i] = *(const bf16x8*)(Ab + row*128 + (((h*4 + (lane>>4)) ^ (row & 7)) << 4));
      }
      #pragma unroll
      for (int j = 0; j < NJ; ++j){
        int row = wn + j*16 + (lane & 15);
        bfr[j] = *(const bf16x8*)(Bb + row*128 + (((h*4 + (lane>>4)) ^ (row & 7)) << 4));
      }
      #pragma unroll
      for (int i = 0; i < 4; ++i)
        #pragma unroll
        for (int j = 0; j < NJ; ++j)
          acc[i][j] = __builtin_amdgcn_mfma_f32_16x16x32_bf16(af[i], bfr[j], acc[i][j], 0, 0, 0);
    }
  };

  if constexpr (CID==3){
    #pragma unroll
    for (int s = 0; s < NSTEP; ++s){
      if (s) __syncthreads();
      stage(0, s);
      __syncthreads();
      compute(0);
    }
  } else {
    stage(0, 0);
    __syncthreads();
    for (int s = 0; s < NSTEP; ++s){
      if (s + 1 < NSTEP) stage((s+1) & 1, s+1);
      compute(s & 1);
      __syncthreads();
    }
  }

  // ---- epilogue (C/D: col=lane&15 -> n, row=(lane>>4)*4+q -> m) ----
  if constexpr (CID==1 || CID==2){
    float badd = s0[0] + s1[0];
    #pragma unroll
    for (int i = 0; i < 4; ++i){
      int o = m0 + wm + i*16 + ((lane >> 4) << 2);
      #pragma unroll
      for (int j = 0; j < NJ; ++j){
        uint32_t n = n0 + wn + j*16 + (lane & 15);
        size_t rn;
        if constexpr (CID==1){
          uint32_t b = n / 196u, p = n - b*196u;
          uint32_t py = p / 14u, px = p - py*14u;
          rn = (size_t)b*256 + (py+1)*16 + (px+1);
        } else rn = n;
        ushort4 pk;
        #pragma unroll
        for (int q = 0; q < 4; ++q) ((u16*)&pk)[q] = f2bf(acc[i][j][q] + badd);
        *(ushort4*)(Obf + rn*256 + o) = pk;
      }
    }
  } else {
    float b3 = s0[0], rs = s1[0], rbv = s2[0];
    float* ldsF = (float*)lds;                 // [64][132] padded f32 tile
    #pragma unroll
    for (int pass = 0; pass < 2; ++pass){
      __syncthreads();
      if ((wm >> 6) == pass){
        #pragma unroll
        for (int i = 0; i < 4; ++i){
          int rb = i*16 + ((lane >> 4) << 2);
          #pragma unroll
          for (int j = 0; j < 4; ++j){
            int col = wn + j*16 + (lane & 15);
            #pragma unroll
            for (int q = 0; q < 4; ++q) ldsF[(rb + q)*132 + col] = acc[i][j][q];
          }
        }
      }
      __syncthreads();
      #pragma unroll
      for (int r = 0; r < 8; ++r){
        int row = (w << 4) + ((lane >> 5) << 3) + r;     // 0..63
        int n4  = (lane & 31) << 2;
        float4 v = *(float4*)&ldsF[row*132 + n4];
        uint32_t n = n0 + n4;
        uint32_t b = n / 196u, p = n - b*196u;           // 196 % 4 == 0: no straddle
        int o = m0 + pass*64 + row;
        size_t base = ((size_t)b*1024 + o)*196 + p;
        const u16* xr = xresb + (size_t)n*1024 + o;      // bf16 residual [n][o]
        float4 ov;
        ov.x = fmaxf((v.x + b3)*rs + rbv + bf2f(xr[0]),    0.f);
        ov.y = fmaxf((v.y + b3)*rs + rbv + bf2f(xr[1024]), 0.f);
        ov.z = fmaxf((v.z + b3)*rs + rbv + bf2f(xr[2048]), 0.f);
        ov.w = fmaxf((v.w + b3)*rs + rbv + bf2f(xr[3072]), 0.f);
        *(float4*)&Of32[base] = ov;
      }
    }
  }
}

__global__ __launch_bounds__(256, 3) void gemm1_conv(
    const u16* __restrict__ A, const u16* __restrict__ B, u16* __restrict__ O,
    const float* __restrict__ s0, const float* __restrict__ s1){
  gemm_body<1>(A, B, O, nullptr, nullptr, s0, s1, nullptr);
}
__global__ __launch_bounds__(256, 3) void gemm2_conv(
    const u16* __restrict__ A, const u16* __restrict__ B, u16* __restrict__ O,
    const float* __restrict__ s0, const float* __restrict__ s1){
  gemm_body<2>(A, B, O, nullptr, nullptr, s0, s1, nullptr);
}
__global__ __launch_bounds__(256, 4) void gemm3_conv(
    const u16* __restrict__ A, const u16* __restrict__ B, const u16* __restrict__ xresb,
    float* __restrict__ O, const float* __restrict__ s0, const float* __restrict__ s1,
    const float* __restrict__ s2){
  gemm_body<3>(A, B, nullptr, O, xresb, s0, s1, s2);
}

// ---------------------------------------------------------------------------
extern "C" void kernel_launch(void* const* d_in, const int* in_sizes, int n_in,
                              void* d_out, int out_size, void* d_ws, size_t ws_size,
                              hipStream_t stream){
  (void)in_sizes; (void)n_in; (void)out_size; (void)ws_size;
  const float* x   = (const float*)d_in[0];
  const float* w1  = (const float*)d_in[1];
  const float* w2  = (const float*)d_in[2];
  const float* w3  = (const float*)d_in[3];
  const float* b1b = (const float*)d_in[4];
  const float* b2a = (const float*)d_in[5];
  const float* b2b = (const float*)d_in[6];
  const float* b3a = (const float*)d_in[7];
  const float* b3b = (const float*)d_in[8];
  const float* rsc = (const float*)d_in[9];
  const float* rbi = (const float*)d_in[10];

  // ws layout (bytes):
  //   xp1 @ 0         : 32768 padded rows x 512B  = 16,777,216
  //   xp2 @ 16777216  : 25088 rows x 512B        = 12,845,056
  //   xp0 @ 29622272  : 25088 rows x 2048B       = 51,380,224
  //   wb1 @ 81002496  : 524,288
  //   wb2 @ 81526784  : 1,179,648
  //   wb3 @ 82706432  : 524,288   (total ~83.2 MB)
  char* ws  = (char*)d_ws;
  u16*  xp1 = (u16*)ws;
  u16*  xp2 = (u16*)(ws + 16777216);
  u16*  xp0 = (u16*)(ws + 29622272);
  u16*  wb1 = (u16*)(ws + 81002496);
  u16*  wb2 = (u16*)(ws + 81526784);
  u16*  wb3 = (u16*)(ws + 82706432);

  prep_all   <<<dim3(5312),   256, 0, stream>>>(w1, w2, w3, wb1, wb2, wb3, xp1);
  transform_x<<<dim3(16,128), 256, 0, stream>>>(x, xp0);

  gemm1_conv<<<dim3(784),  256, 0, stream>>>(wb1, xp0, xp1, b1b, b2a);
  gemm2_conv<<<dim3(784),  256, 0, stream>>>(wb2, xp1, xp2, b2b, b3a);
  gemm3_conv<<<dim3(1568), 256, 0, stream>>>(wb3, xp2, xp0, (float*)d_out, b3b, rsc, rbi);
}

// Round 5
// 320.032 us; speedup vs baseline: 1.0663x; 1.0372x over previous
//
#include <hip/hip_runtime.h>
#include <stdint.h>

typedef __bf16 bf16x8 __attribute__((ext_vector_type(8)));
typedef float f32x4 __attribute__((ext_vector_type(4)));
typedef unsigned short u16;

__device__ __forceinline__ u16 f2bf(float f){
  uint32_t u = __float_as_uint(f);
  u = (u + 0x7fffu + ((u >> 16) & 1u)) >> 16;
  return (u16)u;
}
__device__ __forceinline__ float bf2f(u16 v){
  return __uint_as_float(((uint32_t)v) << 16);
}
__device__ __forceinline__ void gl_lds16(const void* g, void* l){
  __builtin_amdgcn_global_load_lds((const __attribute__((address_space(1))) void*)g,
                                   (__attribute__((address_space(3))) void*)l, 16, 0, 0);
}

// ---------------------------------------------------------------------------
// Weight prep: w1/w3 cvt, w2 repack [O][kq][C]
// ---------------------------------------------------------------------------
__global__ __launch_bounds__(256) void prep_w(
    const float* __restrict__ w1, const float* __restrict__ w2,
    const float* __restrict__ w3, u16* __restrict__ wb1, u16* __restrict__ wb2,
    u16* __restrict__ wb3){
  int bid = blockIdx.x, t = threadIdx.x;
  if (bid < 1024){
    int i = bid*256 + t; wb1[i] = f2bf(w1[i]);
  } else if (bid < 3328){
    int i = (bid-1024)*256 + t;
    int o = i / 2304, r = i - o*2304, kq = r >> 8, c = r & 255;
    wb2[i] = f2bf(w2[((size_t)o*256 + c)*9 + kq]);
  } else {
    int i = (bid-3328)*256 + t; wb3[i] = f2bf(w3[i]);
  }
}

// ---------------------------------------------------------------------------
// x [128][1024][196] f32 NCHW -> xp0 [b*196+p][1024] bf16
// ---------------------------------------------------------------------------
__global__ __launch_bounds__(256) void transform_x(const float* __restrict__ x,
                                                   u16* __restrict__ xp0){
  __shared__ float lds[64*201];
  const int b = blockIdx.y, c0 = blockIdx.x*64, t = threadIdx.x;
  const float4* src = (const float4*)x + (size_t)b*50176 + (size_t)c0*49;
  #pragma unroll
  for (int r = 0; r < 13; ++r){
    int q = r*256 + t;
    if (q < 3136){
      unsigned c = (unsigned)q / 49u, f = (unsigned)q - c*49u;
      float4 v = src[q];
      float* d = &lds[c*201 + f*4];
      d[0]=v.x; d[1]=v.y; d[2]=v.z; d[3]=v.w;
    }
  }
  __syncthreads();
  const int c4 = (t & 15)*4, pg = t >> 4;
  #pragma unroll
  for (int r = 0; r < 13; ++r){
    int p = r*16 + pg;
    if (p < 196){
      ushort4 pk;
      ((u16*)&pk)[0] = f2bf(lds[(c4+0)*201 + p]);
      ((u16*)&pk)[1] = f2bf(lds[(c4+1)*201 + p]);
      ((u16*)&pk)[2] = f2bf(lds[(c4+2)*201 + p]);
      ((u16*)&pk)[3] = f2bf(lds[(c4+3)*201 + p]);
      *(ushort4*)&xp0[((size_t)b*196 + p)*1024 + c0 + c4] = pk;
    }
  }
}

// ---------------------------------------------------------------------------
// conv1 1x1: per-batch block. grid 256 = (128 b) x (2 m-halves), 512 threads.
// N = 256 padded-grid positions (borders computed-garbage, written as 0).
// LDS (dyn 98304): A dbuf 2x16K @0, B dbuf 2x32K @32768.
// ---------------------------------------------------------------------------
__global__ __launch_bounds__(512, 1) void gemm1_conv(
    const u16* __restrict__ A, const u16* __restrict__ B, u16* __restrict__ O,
    const float* __restrict__ s0, const float* __restrict__ s1){
  extern __shared__ char lds[];
  const int t = threadIdx.x, lane = t & 63, w = t >> 6;
  const int wm = (w >> 2) * 64, wn = (w & 3) * 64;
  const int b = blockIdx.x & 127, m0 = (blockIdx.x >> 7) * 128;
  f32x4 acc[4][4] = {};

  uint32_t aoff[2], boff[4];
  #pragma unroll
  for (int i = 0; i < 2; ++i){
    int gl = i*512 + t, row = gl >> 3, ss = gl & 7;
    aoff[i] = (uint32_t)(m0 + row)*2048 + ((ss ^ (row & 7)) << 4);
  }
  #pragma unroll
  for (int i = 0; i < 4; ++i){
    int gl = i*512 + t, row = gl >> 3, ss = gl & 7;   // row = grid pos 0..255
    int y = row >> 4, x = row & 15;
    int p = ((unsigned)(y-1) < 14u && (unsigned)(x-1) < 14u) ? (y-1)*14 + (x-1) : 0;
    boff[i] = ((uint32_t)b*196 + p)*2048 + ((ss ^ (row & 7)) << 4);
  }

  auto stage = [&](int buf, int kc){
    char* Ab = lds + buf*16384;
    char* Bb = lds + 32768 + buf*32768;
    #pragma unroll
    for (int i = 0; i < 2; ++i)
      gl_lds16((const char*)A + aoff[i] + kc*128, Ab + (i*512 + t)*16);
    #pragma unroll
    for (int i = 0; i < 4; ++i)
      gl_lds16((const char*)B + boff[i] + kc*128, Bb + (i*512 + t)*16);
  };
  auto compute = [&](int buf){
    char* Ab = lds + buf*16384;
    char* Bb = lds + 32768 + buf*32768;
    #pragma unroll
    for (int h = 0; h < 2; ++h){
      bf16x8 af[4], bfr[4];
      #pragma unroll
      for (int i = 0; i < 4; ++i){
        int row = wm + i*16 + (lane & 15);
        af[i] = *(const bf16x8*)(Ab + row*128 + (((h*4 + (lane>>4)) ^ (row & 7)) << 4));
      }
      #pragma unroll
      for (int j = 0; j < 4; ++j){
        int row = wn + j*16 + (lane & 15);
        bfr[j] = *(const bf16x8*)(Bb + row*128 + (((h*4 + (lane>>4)) ^ (row & 7)) << 4));
      }
      #pragma unroll
      for (int i = 0; i < 4; ++i)
        #pragma unroll
        for (int j = 0; j < 4; ++j)
          acc[i][j] = __builtin_amdgcn_mfma_f32_16x16x32_bf16(af[i], bfr[j], acc[i][j], 0, 0, 0);
    }
  };

  stage(0, 0);
  __syncthreads();
  #pragma unroll
  for (int kc = 0; kc < 16; ++kc){
    if (kc < 15) stage((kc+1) & 1, kc+1);
    compute(kc & 1);
    __syncthreads();
  }

  float badd = s0[0] + s1[0];
  #pragma unroll
  for (int i = 0; i < 4; ++i){
    int o = m0 + wm + i*16 + ((lane >> 4) << 2);
    #pragma unroll
    for (int j = 0; j < 4; ++j){
      int n = wn + j*16 + (lane & 15);
      int y = n >> 4, x = n & 15;
      bool real = ((unsigned)(y-1) < 14u) && ((unsigned)(x-1) < 14u);
      ushort4 pk;
      #pragma unroll
      for (int q = 0; q < 4; ++q)
        ((u16*)&pk)[q] = real ? f2bf(acc[i][j][q] + badd) : (u16)0;
      *(ushort4*)(O + ((size_t)b*256 + n)*256 + o) = pk;
    }
  }
}

// ---------------------------------------------------------------------------
// conv2 3x3: per-batch block. grid 256, 512 threads. B = batch's padded grid
// + 18-row guards staged ONCE per 64-chan chunk; 9 shifts = LDS row offsets.
// LDS (dyn 107520): A dbuf 2x16K @0; B dbuf 2x37376 @32768 (292 rows x 128B).
// ---------------------------------------------------------------------------
__global__ __launch_bounds__(512, 1) void gemm2_conv(
    const u16* __restrict__ A, const u16* __restrict__ B, u16* __restrict__ O,
    const float* __restrict__ s0, const float* __restrict__ s1){
  extern __shared__ char lds[];
  const int t = threadIdx.x, lane = t & 63, w = t >> 6;
  const int wm = (w >> 2) * 64, wn = (w & 3) * 64;
  const int b = blockIdx.x & 127, m0 = (blockIdx.x >> 7) * 128;
  f32x4 acc[4][4] = {};

  uint32_t aoff[2], boff[5];
  #pragma unroll
  for (int i = 0; i < 2; ++i){
    int gl = i*512 + t, row = gl >> 3, ss = gl & 7;
    aoff[i] = (uint32_t)(m0 + row)*4608 + ((ss ^ (row & 7)) << 4);
  }
  #pragma unroll
  for (int i = 0; i < 5; ++i){
    int gl = i*512 + t, row = gl >> 3, ss = gl & 7;   // LDS row 0..291
    int pos = row - 18;
    pos = pos < 0 ? 0 : (pos > 255 ? 255 : pos);      // guards: clamped (finite garbage)
    boff[i] = ((uint32_t)b*256 + pos)*512 + ((ss ^ (row & 7)) << 4);
  }

  auto stageA = [&](int buf, int kq, int kc){
    char* Ab = lds + buf*16384;
    int off = kq*512 + kc*128;
    #pragma unroll
    for (int i = 0; i < 2; ++i)
      gl_lds16((const char*)A + aoff[i] + off, Ab + (i*512 + t)*16);
  };
  auto stageB = [&](int buf, int kc){
    char* Bb = lds + 32768 + buf*37376;
    #pragma unroll
    for (int i = 0; i < 5; ++i){
      int gl = i*512 + t;
      if (gl < 2336) gl_lds16((const char*)B + boff[i] + kc*128, Bb + gl*16);
    }
  };
  auto compute = [&](int ab, int bb, int shift){
    char* Ab = lds + ab*16384;
    char* Bb = lds + 32768 + bb*37376;
    #pragma unroll
    for (int h = 0; h < 2; ++h){
      bf16x8 af[4], bfr[4];
      #pragma unroll
      for (int i = 0; i < 4; ++i){
        int row = wm + i*16 + (lane & 15);
        af[i] = *(const bf16x8*)(Ab + row*128 + (((h*4 + (lane>>4)) ^ (row & 7)) << 4));
      }
      #pragma unroll
      for (int j = 0; j < 4; ++j){
        int row = 18 + wn + j*16 + (lane & 15) + shift;
        bfr[j] = *(const bf16x8*)(Bb + row*128 + (((h*4 + (lane>>4)) ^ (row & 7)) << 4));
      }
      #pragma unroll
      for (int i = 0; i < 4; ++i)
        #pragma unroll
        for (int j = 0; j < 4; ++j)
          acc[i][j] = __builtin_amdgcn_mfma_f32_16x16x32_bf16(af[i], bfr[j], acc[i][j], 0, 0, 0);
    }
  };

  stageB(0, 0); stageA(0, 0, 0);
  __syncthreads();
  int ab = 0, bbuf = 0;
  #pragma unroll
  for (int kc = 0; kc < 4; ++kc){
    #pragma unroll
    for (int kq = 0; kq < 9; ++kq){
      if (kq < 8) stageA(ab ^ 1, kq + 1, kc);
      else if (kc < 3){ stageB(bbuf ^ 1, kc + 1); stageA(ab ^ 1, 0, kc + 1); }
      compute(ab, bbuf, (kq/3 - 1)*16 + (kq%3) - 1);
      __syncthreads();
      ab ^= 1;
      if (kq == 8) bbuf ^= 1;
    }
  }

  float badd = s0[0] + s1[0];
  #pragma unroll
  for (int i = 0; i < 4; ++i){
    int o = m0 + wm + i*16 + ((lane >> 4) << 2);
    #pragma unroll
    for (int j = 0; j < 4; ++j){
      int n = wn + j*16 + (lane & 15);
      int y = n >> 4, x = n & 15;
      if (((unsigned)(y-1) < 14u) && ((unsigned)(x-1) < 14u)){
        int p = (y-1)*14 + (x-1);
        ushort4 pk;
        #pragma unroll
        for (int q = 0; q < 4; ++q) ((u16*)&pk)[q] = f2bf(acc[i][j][q] + badd);
        *(ushort4*)(O + ((size_t)b*196 + p)*256 + o) = pk;
      }
    }
  }
}

// ---------------------------------------------------------------------------
// conv3 1x1 + scale/bias/residual-ReLU (round-4 structure, bf16 residual)
// BM=128 BN=128 single-buf; LDS-transposed f32 epilogue, float4 stores.
// ---------------------------------------------------------------------------
__global__ __launch_bounds__(256, 4) void gemm3_conv(
    const u16* __restrict__ A, const u16* __restrict__ B, const u16* __restrict__ xresb,
    float* __restrict__ Of32, const float* __restrict__ s0, const float* __restrict__ s1,
    const float* __restrict__ s2){
  __shared__ char lds[33792];
  const int t = threadIdx.x, lane = t & 63, w = t >> 6;
  const int wm = (w >> 1) * 64, wn = (w & 1) * 64;
  const int orig = blockIdx.x;
  const int bid  = (orig & 7) * ((int)gridDim.x >> 3) + (orig >> 3);
  const int n0 = (bid >> 3) * 128, m0 = (bid & 7) * 128;
  f32x4 acc[4][4] = {};

  uint32_t aoff[4], boff[4];
  #pragma unroll
  for (int i = 0; i < 4; ++i){
    int gl = i*256 + t, row = gl >> 3, ss = gl & 7;
    int xo = (ss ^ (row & 7)) << 4;
    aoff[i] = (uint32_t)(m0 + row)*512 + xo;
    boff[i] = (uint32_t)(n0 + row)*512 + xo;
  }

  auto stage = [&](int s){
    char* Ab = lds;
    char* Bb = lds + 16384;
    #pragma unroll
    for (int i = 0; i < 4; ++i){
      gl_lds16((const char*)A + aoff[i] + s*128, Ab + (i*256 + t)*16);
      gl_lds16((const char*)B + boff[i] + s*128, Bb + (i*256 + t)*16);
    }
  };
  auto compute = [&](){
    char* Ab = lds;
    char* Bb = lds + 16384;
    #pragma unroll
    for (int h = 0; h < 2; ++h){
      bf16x8 af[4], bfr[4];
      #pragma unroll
      for (int i = 0; i < 4; ++i){
        int row = wm + i*16 + (lane & 15);
        af[i] = *(const bf16x8*)(Ab + row*128 + (((h*4 + (lane>>4)) ^ (row & 7)) << 4));
      }
      #pragma unroll
      for (int j = 0; j < 4; ++j){
        int row = wn + j*16 + (lane & 15);
        bfr[j] = *(const bf16x8*)(Bb + row*128 + (((h*4 + (lane>>4)) ^ (row & 7)) << 4));
      }
      #pragma unroll
      for (int i = 0; i < 4; ++i)
        #pragma unroll
        for (int j = 0; j < 4; ++j)
          acc[i][j] = __builtin_amdgcn_mfma_f32_16x16x32_bf16(af[i], bfr[j], acc[i][j], 0, 0, 0);
    }
  };

  #pragma unroll
  for (int s = 0; s < 4; ++s){
    if (s) __syncthreads();
    stage(s);
    __syncthreads();
    compute();
  }

  float b3 = s0[0], rs = s1[0], rbv = s2[0];
  float* ldsF = (float*)lds;                 // [64][132] padded f32 tile
  #pragma unroll
  for (int pass = 0; pass < 2; ++pass){
    __syncthreads();
    if ((wm >> 6) == pass){
      #pragma unroll
      for (int i = 0; i < 4; ++i){
        int rb = i*16 + ((lane >> 4) << 2);
        #pragma unroll
        for (int j = 0; j < 4; ++j){
          int col = wn + j*16 + (lane & 15);
          #pragma unroll
          for (int q = 0; q < 4; ++q) ldsF[(rb + q)*132 + col] = acc[i][j][q];
        }
      }
    }
    __syncthreads();
    #pragma unroll
    for (int r = 0; r < 8; ++r){
      int row = (w << 4) + ((lane >> 5) << 3) + r;     // 0..63
      int n4  = (lane & 31) << 2;
      float4 v = *(float4*)&ldsF[row*132 + n4];
      uint32_t n = n0 + n4;
      uint32_t b = n / 196u, p = n - b*196u;           // 196 % 4 == 0: no straddle
      int o = m0 + pass*64 + row;
      size_t base = ((size_t)b*1024 + o)*196 + p;
      const u16* xr = xresb + (size_t)n*1024 + o;      // bf16 residual [n][o]
      float4 ov;
      ov.x = fmaxf((v.x + b3)*rs + rbv + bf2f(xr[0]),    0.f);
      ov.y = fmaxf((v.y + b3)*rs + rbv + bf2f(xr[1024]), 0.f);
      ov.z = fmaxf((v.z + b3)*rs + rbv + bf2f(xr[2048]), 0.f);
      ov.w = fmaxf((v.w + b3)*rs + rbv + bf2f(xr[3072]), 0.f);
      *(float4*)&Of32[base] = ov;
    }
  }
}

// ---------------------------------------------------------------------------
extern "C" void kernel_launch(void* const* d_in, const int* in_sizes, int n_in,
                              void* d_out, int out_size, void* d_ws, size_t ws_size,
                              hipStream_t stream){
  (void)in_sizes; (void)n_in; (void)out_size; (void)ws_size;
  const float* x   = (const float*)d_in[0];
  const float* w1  = (const float*)d_in[1];
  const float* w2  = (const float*)d_in[2];
  const float* w3  = (const float*)d_in[3];
  const float* b1b = (const float*)d_in[4];
  const float* b2a = (const float*)d_in[5];
  const float* b2b = (const float*)d_in[6];
  const float* b3a = (const float*)d_in[7];
  const float* b3b = (const float*)d_in[8];
  const float* rsc = (const float*)d_in[9];
  const float* rbi = (const float*)d_in[10];

  // ws layout (bytes):
  //   xp1 @ 0         : [128 b][256 gridpos][256 ch] bf16 = 16,777,216
  //   xp2 @ 16777216  : [25088][256] bf16              = 12,845,056
  //   xp0 @ 29622272  : [25088][1024] bf16             = 51,380,224
  //   wb1 @ 81002496  : 524,288 | wb2 @ 81526784 : 1,179,648 | wb3 @ 82706432 : 524,288
  char* ws  = (char*)d_ws;
  u16*  xp1 = (u16*)ws;
  u16*  xp2 = (u16*)(ws + 16777216);
  u16*  xp0 = (u16*)(ws + 29622272);
  u16*  wb1 = (u16*)(ws + 81002496);
  u16*  wb2 = (u16*)(ws + 81526784);
  u16*  wb3 = (u16*)(ws + 82706432);

  prep_w     <<<dim3(4352),   256, 0, stream>>>(w1, w2, w3, wb1, wb2, wb3);
  transform_x<<<dim3(16,128), 256, 0, stream>>>(x, xp0);

  gemm1_conv<<<dim3(256),  512,  98304, stream>>>(wb1, xp0, xp1, b1b, b2a);
  gemm2_conv<<<dim3(256),  512, 107520, stream>>>(wb2, xp1, xp2, b2b, b3a);
  gemm3_conv<<<dim3(1568), 256,      0, stream>>>(wb3, xp2, xp0, (float*)d_out, b3b, rsc, rbi);
}